// Round 2
// baseline (66.710 us; speedup 1.0000x reference)
//
#include <hip/hip_runtime.h>

#define NSPIN   64
#define BATCH_N 1000000
#define NTILES  (BATCH_N / 16)    // 62500 16-row tiles
#define NBLOCKS 3125
#define NWAVES  (NBLOCKS * 4)     // 12500 waves -> exactly 5 tiles/wave
#define TPW     (NTILES / NWAVES) // 5

typedef __bf16 bf16x8 __attribute__((ext_vector_type(8)));
typedef float  f32x4  __attribute__((ext_vector_type(4)));

// Build symmetric bf16 J (zero diag) from lower-tri coupling vector.
__global__ void build_J_kernel(const float* __restrict__ couplings,
                               __bf16* __restrict__ Jg) {
    int idx = blockIdx.x * blockDim.x + threadIdx.x;
    if (idx >= NSPIN * NSPIN) return;
    int r = idx >> 6, c = idx & 63;
    float v = 0.0f;
    if (r > c)      v = couplings[(r * (r - 1)) / 2 + c];
    else if (r < c) v = couplings[(c * (c - 1)) / 2 + r];
    Jg[idx] = (__bf16)v;
}

__device__ __forceinline__ unsigned fbits(float x) {
    union { float f; unsigned u; } cv; cv.f = x; return cv.u;
}
// pack two fp32 into packed bf16x2 (truncation — exact for +/-1.0)
__device__ __forceinline__ unsigned pack2(float lo, float hi) {
    return __builtin_amdgcn_perm(fbits(hi), fbits(lo), 0x07060302u);
}

// Load one 16x64 fp32 tile's fragments for this lane.
// a[0..3]: A-operand rows (row=lo16, k = g4*8 + e, kb in {0,1})
// r[nb][q]: re-read s[4*g4+q][nb*16+lo16] for the final row-dot
__device__ __forceinline__ void load_tile(const float* __restrict__ S,
                                          int lo16, int g4,
                                          f32x4 a[4], float r[4][4]) {
    const float* arow = S + lo16 * NSPIN + g4 * 8;
    a[0] = *reinterpret_cast<const f32x4*>(arow);
    a[1] = *reinterpret_cast<const f32x4*>(arow + 4);
    a[2] = *reinterpret_cast<const f32x4*>(arow + 32);
    a[3] = *reinterpret_cast<const f32x4*>(arow + 36);
    const float* R = S + g4 * (4 * NSPIN);
#pragma unroll
    for (int nb = 0; nb < 4; ++nb) {
        int col = nb * 16 + lo16;
#pragma unroll
        for (int q = 0; q < 4; ++q)
            r[nb][q] = R[q * NSPIN + col];
    }
}

template<bool USE_WS>
__global__ __launch_bounds__(256, 4) void ham_kernel(
    const float* __restrict__ states,
    const float* __restrict__ couplings,
    const float* __restrict__ fields,
    const __bf16* __restrict__ Jg,
    float* __restrict__ out)
{
    __shared__ bf16x8 Jlds[NSPIN * NSPIN / 8];   // 8 KB, only if !USE_WS
    if constexpr (!USE_WS) {
        __bf16* J = (__bf16*)Jlds;
        for (int i = threadIdx.x; i < NSPIN * NSPIN; i += 256) {
            int r = i >> 6, c = i & 63;
            float v = 0.0f;
            if (r > c)      v = couplings[(r * (r - 1)) / 2 + c];
            else if (r < c) v = couplings[(c * (c - 1)) / 2 + r];
            J[i] = (__bf16)v;
        }
        __syncthreads();
    }

    const int lane = threadIdx.x & 63;
    const int wid  = threadIdx.x >> 6;
    const int lo16 = lane & 15;   // col for B/D, row for A
    const int g4   = lane >> 4;   // k-group / D-row group
    const int gw   = blockIdx.x * 4 + wid;

    // B fragments (hoisted): jf[nb][kb] = J[k=kb*32+g4*8+e][n=nb*16+lo16]
    // = J[n][k] by symmetry -> contiguous row segment, 16B aligned.
    bf16x8 jf[4][2];
#pragma unroll
    for (int nb = 0; nb < 4; ++nb)
#pragma unroll
        for (int kb = 0; kb < 2; ++kb) {
            int off = (nb * 16 + lo16) * NSPIN + kb * 32 + g4 * 8;
            if constexpr (USE_WS) jf[nb][kb] = *reinterpret_cast<const bf16x8*>(Jg + off);
            else                  jf[nb][kb] = Jlds[off / 8];
        }

    float fcol[4];
#pragma unroll
    for (int nb = 0; nb < 4; ++nb) fcol[nb] = fields[nb * 16 + lo16];

    // ---- 2-stage software pipeline over exactly TPW tiles ----
    f32x4 a_cur[4]; float r_cur[4][4];
    load_tile(states + (size_t)gw * (16 * NSPIN), lo16, g4, a_cur, r_cur);

#pragma unroll
    for (int i = 0; i < TPW; ++i) {
        const int t = gw + i * NWAVES;

        // Prefetch next tile before computing current (independent loads;
        // HBM latency overlaps pack/MFMA/reduce below).
        f32x4 a_nxt[4]; float r_nxt[4][4];
        if (i + 1 < TPW)
            load_tile(states + (size_t)(t + NWAVES) * (16 * NSPIN),
                      lo16, g4, a_nxt, r_nxt);

        // fp32 -> packed bf16 A fragments (truncation exact for +/-1)
        union { bf16x8 v; unsigned u[4]; } af0, af1;
        af0.u[0] = pack2(a_cur[0][0], a_cur[0][1]);
        af0.u[1] = pack2(a_cur[0][2], a_cur[0][3]);
        af0.u[2] = pack2(a_cur[1][0], a_cur[1][1]);
        af0.u[3] = pack2(a_cur[1][2], a_cur[1][3]);
        af1.u[0] = pack2(a_cur[2][0], a_cur[2][1]);
        af1.u[1] = pack2(a_cur[2][2], a_cur[2][3]);
        af1.u[2] = pack2(a_cur[3][0], a_cur[3][1]);
        af1.u[3] = pack2(a_cur[3][2], a_cur[3][3]);

        // acc init = f[col]: D = S*J + f (field folded in for free)
        f32x4 acc[4];
#pragma unroll
        for (int nb = 0; nb < 4; ++nb)
            acc[nb] = (f32x4){fcol[nb], fcol[nb], fcol[nb], fcol[nb]};
#pragma unroll
        for (int nb = 0; nb < 4; ++nb) {
            acc[nb] = __builtin_amdgcn_mfma_f32_16x16x32_bf16(af0.v, jf[nb][0], acc[nb], 0, 0, 0);
            acc[nb] = __builtin_amdgcn_mfma_f32_16x16x32_bf16(af1.v, jf[nb][1], acc[nb], 0, 0, 0);
        }

        // H[row] = -sum_col s[row][col]*acc ; D: row=4*g4+q, col=nb*16+lo16
        float p0 = 0.f, p1 = 0.f, p2 = 0.f, p3 = 0.f;
#pragma unroll
        for (int nb = 0; nb < 4; ++nb) {
            p0 += r_cur[nb][0] * acc[nb][0];
            p1 += r_cur[nb][1] * acc[nb][1];
            p2 += r_cur[nb][2] * acc[nb][2];
            p3 += r_cur[nb][3] * acc[nb][3];
        }
#pragma unroll
        for (int m = 1; m <= 8; m <<= 1) {
            p0 += __shfl_xor(p0, m, 64);
            p1 += __shfl_xor(p1, m, 64);
            p2 += __shfl_xor(p2, m, 64);
            p3 += __shfl_xor(p3, m, 64);
        }
        if (lo16 < 4) {
            float v = (lo16 == 0) ? p0 : (lo16 == 1) ? p1 : (lo16 == 2) ? p2 : p3;
            out[t * 16 + g4 * 4 + lo16] = -v;
        }

        // rotate pipeline regs (vanishes under full unroll)
        if (i + 1 < TPW) {
#pragma unroll
            for (int k = 0; k < 4; ++k) {
                a_cur[k] = a_nxt[k];
#pragma unroll
                for (int q = 0; q < 4; ++q) r_cur[k][q] = r_nxt[k][q];
            }
        }
    }
}

extern "C" void kernel_launch(void* const* d_in, const int* in_sizes, int n_in,
                              void* d_out, int out_size, void* d_ws, size_t ws_size,
                              hipStream_t stream) {
    const float* states    = (const float*)d_in[0];
    const float* couplings = (const float*)d_in[1];
    const float* fields    = (const float*)d_in[2];
    float* out = (float*)d_out;

    if (ws_size >= NSPIN * NSPIN * sizeof(__bf16)) {
        __bf16* Jg = (__bf16*)d_ws;
        build_J_kernel<<<16, 256, 0, stream>>>(couplings, Jg);
        ham_kernel<true><<<NBLOCKS, 256, 0, stream>>>(states, couplings, fields, Jg, out);
    } else {
        ham_kernel<false><<<NBLOCKS, 256, 0, stream>>>(states, couplings, fields, nullptr, out);
    }
}

// Round 3
// 52.701 us; speedup vs baseline: 1.2658x; 1.2658x over previous
//
#include <hip/hip_runtime.h>

#define NSPIN   64
#define BATCH_N 1000000
#define NTILES  (BATCH_N / 16)    // 62500 16-row tiles
#define NBLOCKS 3125
#define NWAVES  (NBLOCKS * 4)     // 12500 waves
#define TPW     (NTILES / NWAVES) // exactly 5 tiles/wave

typedef __bf16 bf16x8 __attribute__((ext_vector_type(8)));
typedef float  f32x4  __attribute__((ext_vector_type(4)));

__device__ __forceinline__ unsigned fbits(float x) {
    union { float f; unsigned u; } cv; cv.f = x; return cv.u;
}
// pack two fp32 into packed bf16x2 (truncation — exact for +/-1.0)
__device__ __forceinline__ unsigned pack2(float lo, float hi) {
    return __builtin_amdgcn_perm(fbits(hi), fbits(lo), 0x07060302u);
}

// async global->LDS, 16B per lane; LDS dest = uniform base + lane*16
__device__ __forceinline__ void gload_lds16(const void* g, void* l) {
    __builtin_amdgcn_global_load_lds(
        (const __attribute__((address_space(1))) unsigned int*)g,
        (__attribute__((address_space(3))) unsigned int*)l, 16, 0, 0);
}

__global__ __launch_bounds__(256, 4) void ham_kernel(
    const float* __restrict__ states,
    const float* __restrict__ couplings,
    const float* __restrict__ fields,
    float* __restrict__ out)
{
    // [0,8K): J bf16[64][64] during init; afterwards the whole 32K is
    // 4 waves x 2 x 4KB private staging double-buffers (wave w at w*8K).
    __shared__ char smem[32 * 1024];

    {   // build symmetric J (zero diag) from lower-tri couplings
        __bf16* J = (__bf16*)smem;
        for (int i = threadIdx.x; i < NSPIN * NSPIN; i += 256) {
            int r = i >> 6, c = i & 63;
            float v = 0.0f;
            if (r > c)      v = couplings[(r * (r - 1)) / 2 + c];
            else if (r < c) v = couplings[(c * (c - 1)) / 2 + r];
            J[i] = (__bf16)v;
        }
    }
    __syncthreads();

    const int lane = threadIdx.x & 63;
    const int wid  = threadIdx.x >> 6;
    const int lo16 = lane & 15;   // B/D col; A row
    const int g4   = lane >> 4;   // k-group / D-row group
    const int gw   = blockIdx.x * 4 + wid;

    // Hoist B fragments: jf[nb][kb] = J[k=kb*32+g4*8+e][n=16nb+lo16]
    // = J[n][k] by symmetry -> contiguous 16B row segment.
    bf16x8 jf[4][2];
    {
        const __bf16* J = (const __bf16*)smem;
#pragma unroll
        for (int nb = 0; nb < 4; ++nb)
#pragma unroll
            for (int kb = 0; kb < 2; ++kb)
                jf[nb][kb] = *(const bf16x8*)(J + (nb * 16 + lo16) * NSPIN + kb * 32 + g4 * 8);
    }
    float fcol[4];
#pragma unroll
    for (int nb = 0; nb < 4; ++nb) fcol[nb] = fields[nb * 16 + lo16];

    __syncthreads();   // J region is now free -> becomes wave0's buffers

    char* mybuf = smem + wid * 8192;   // two 4KB buffers, wave-private

    // Per-lane swizzled global source offsets for the 4 staging instrs.
    // LDS[row][chunk] = G[row][chunk ^ (row&7)]  (16B chunks, XOR involution)
    int srcoff[4];
#pragma unroll
    for (int j = 0; j < 4; ++j) {
        int row   = 4 * j + (lane >> 4);
        int chunk = (lane & 15) ^ (row & 7);
        srcoff[j] = row * 256 + chunk * 16;
    }

    const char* sbase = (const char*)states;
    auto stage = [&](int buf, int t) {
        const char* src = sbase + (size_t)t * 4096;
#pragma unroll
        for (int j = 0; j < 4; ++j)
            gload_lds16(src + srcoff[j], mybuf + buf * 4096 + j * 1024);
    };
    // swizzled LDS read address for element at (row, byte col c)
    auto lds_at = [&](const char* B, int row, int c) -> const void* {
        return (const void*)(B + row * 256 + (c ^ ((row & 7) << 4)));
    };

    stage(0, gw);   // prologue

#pragma unroll
    for (int i = 0; i < TPW; ++i) {
        const int t = gw + i * NWAVES;
        if (i + 1 < TPW) {
            stage((i + 1) & 1, t + NWAVES);          // prefetch next tile
            asm volatile("s_waitcnt vmcnt(4)" ::: "memory");  // cur staged
        } else {
            asm volatile("s_waitcnt vmcnt(0)" ::: "memory");
        }
        __builtin_amdgcn_sched_barrier(0);

        const char* B = mybuf + (i & 1) * 4096;

        // A fragments from LDS (swizzled, conflict-spread b128 reads)
        f32x4 a0 = *(const f32x4*)lds_at(B, lo16, g4 * 32);
        f32x4 a1 = *(const f32x4*)lds_at(B, lo16, g4 * 32 + 16);
        f32x4 a2 = *(const f32x4*)lds_at(B, lo16, 128 + g4 * 32);
        f32x4 a3 = *(const f32x4*)lds_at(B, lo16, 128 + g4 * 32 + 16);

        // re-read values for the row-dot, now from LDS not global
        float rv[4][4];
#pragma unroll
        for (int nb = 0; nb < 4; ++nb)
#pragma unroll
            for (int q = 0; q < 4; ++q)
                rv[nb][q] = *(const float*)lds_at(B, 4 * g4 + q, (nb * 16 + lo16) * 4);

        union { bf16x8 v; unsigned u[4]; } af0, af1;
        af0.u[0] = pack2(a0[0], a0[1]);
        af0.u[1] = pack2(a0[2], a0[3]);
        af0.u[2] = pack2(a1[0], a1[1]);
        af0.u[3] = pack2(a1[2], a1[3]);
        af1.u[0] = pack2(a2[0], a2[1]);
        af1.u[1] = pack2(a2[2], a2[3]);
        af1.u[2] = pack2(a3[0], a3[1]);
        af1.u[3] = pack2(a3[2], a3[3]);

        // D = S*J + f  (field folded into acc init)
        f32x4 acc[4];
#pragma unroll
        for (int nb = 0; nb < 4; ++nb)
            acc[nb] = (f32x4){fcol[nb], fcol[nb], fcol[nb], fcol[nb]};
#pragma unroll
        for (int nb = 0; nb < 4; ++nb) {
            acc[nb] = __builtin_amdgcn_mfma_f32_16x16x32_bf16(af0.v, jf[nb][0], acc[nb], 0, 0, 0);
            acc[nb] = __builtin_amdgcn_mfma_f32_16x16x32_bf16(af1.v, jf[nb][1], acc[nb], 0, 0, 0);
        }

        // H[row] = -sum_col s[row][col]*acc ; D: row=4*g4+q, col=16nb+lo16
        float p0 = 0.f, p1 = 0.f, p2 = 0.f, p3 = 0.f;
#pragma unroll
        for (int nb = 0; nb < 4; ++nb) {
            p0 += rv[nb][0] * acc[nb][0];
            p1 += rv[nb][1] * acc[nb][1];
            p2 += rv[nb][2] * acc[nb][2];
            p3 += rv[nb][3] * acc[nb][3];
        }
#pragma unroll
        for (int m = 1; m <= 8; m <<= 1) {
            p0 += __shfl_xor(p0, m, 64);
            p1 += __shfl_xor(p1, m, 64);
            p2 += __shfl_xor(p2, m, 64);
            p3 += __shfl_xor(p3, m, 64);
        }
        if (lo16 < 4) {
            float v = (lo16 == 0) ? p0 : (lo16 == 1) ? p1 : (lo16 == 2) ? p2 : p3;
            out[t * 16 + g4 * 4 + lo16] = -v;
        }
    }
}

extern "C" void kernel_launch(void* const* d_in, const int* in_sizes, int n_in,
                              void* d_out, int out_size, void* d_ws, size_t ws_size,
                              hipStream_t stream) {
    const float* states    = (const float*)d_in[0];
    const float* couplings = (const float*)d_in[1];
    const float* fields    = (const float*)d_in[2];
    float* out = (float*)d_out;
    ham_kernel<<<NBLOCKS, 256, 0, stream>>>(states, couplings, fields, out);
}

// Round 4
// 50.202 us; speedup vs baseline: 1.3288x; 1.0498x over previous
//
#include <hip/hip_runtime.h>

#define NSPIN   64
#define BATCH_N 1000000
#define NTILES  (BATCH_N / 16)    // 62500 16-row tiles
#define NBLOCKS 3125
#define NWAVES  (NBLOCKS * 4)     // 12500 waves
#define TPW     (NTILES / NWAVES) // exactly 5 tiles/wave

typedef __bf16 bf16x8 __attribute__((ext_vector_type(8)));
typedef float  f32x4  __attribute__((ext_vector_type(4)));

__device__ __forceinline__ unsigned fbits(float x) {
    union { float f; unsigned u; } cv; cv.f = x; return cv.u;
}
// pack two fp32 into packed bf16x2 (truncation — exact for +/-1.0)
__device__ __forceinline__ unsigned pack2(float lo, float hi) {
    return __builtin_amdgcn_perm(fbits(hi), fbits(lo), 0x07060302u);
}

// async global->LDS, 16B per lane; LDS dest = uniform base + lane*16
__device__ __forceinline__ void gload_lds16(const void* g, void* l) {
    __builtin_amdgcn_global_load_lds(
        (const __attribute__((address_space(1))) unsigned int*)g,
        (__attribute__((address_space(3))) unsigned int*)l, 16, 0, 0);
}

__global__ __launch_bounds__(256, 4) void ham_kernel(
    const float* __restrict__ states,
    const float* __restrict__ couplings,
    const float* __restrict__ fields,
    float* __restrict__ out)
{
    // [0,8K): J bf16[64][64] during init; afterwards the whole 32K is
    // 4 waves x 2 x 4KB private staging double-buffers (wave w at w*8K).
    __shared__ char smem[32 * 1024];

    {   // build symmetric J (zero diag) from lower-tri couplings
        __bf16* J = (__bf16*)smem;
        for (int i = threadIdx.x; i < NSPIN * NSPIN; i += 256) {
            int r = i >> 6, c = i & 63;
            float v = 0.0f;
            if (r > c)      v = couplings[(r * (r - 1)) / 2 + c];
            else if (r < c) v = couplings[(c * (c - 1)) / 2 + r];
            J[i] = (__bf16)v;
        }
    }
    __syncthreads();

    const int lane = threadIdx.x & 63;
    const int wid  = threadIdx.x >> 6;
    const int lo16 = lane & 15;   // A row (J row within nb-block) / D col (batch)
    const int g4   = lane >> 4;   // k-group; D rows 4*g4+q
    const int gw   = blockIdx.x * 4 + wid;

    // Hoist A fragments (J rows): jf[nb][kb] = J[16nb+lo16][32kb+8g4+e]
    // (symmetric J -> same bytes as before, now used as the A operand)
    bf16x8 jf[4][2];
    {
        const __bf16* J = (const __bf16*)smem;
#pragma unroll
        for (int nb = 0; nb < 4; ++nb)
#pragma unroll
            for (int kb = 0; kb < 2; ++kb)
                jf[nb][kb] = *(const bf16x8*)(J + (nb * 16 + lo16) * NSPIN + kb * 32 + g4 * 8);
    }
    // acc init = fields along m: ffrag[nb][q] = f[16nb+4g4+q] (16B aligned)
    f32x4 ffrag[4];
#pragma unroll
    for (int nb = 0; nb < 4; ++nb)
        ffrag[nb] = *(const f32x4*)(fields + nb * 16 + g4 * 4);

    __syncthreads();   // J region is now free -> becomes wave0's buffers

    char* mybuf = smem + wid * 8192;   // two 4KB buffers, wave-private

    // Per-lane swizzled global source offsets for the 4 staging instrs.
    // LDS[row][chunk] = G[row][chunk ^ (row&7)]  (16B chunks, XOR involution)
    int srcoff[4];
#pragma unroll
    for (int j = 0; j < 4; ++j) {
        int row   = 4 * j + (lane >> 4);
        int chunk = (lane & 15) ^ (row & 7);
        srcoff[j] = row * 256 + chunk * 16;
    }

    const char* sbase = (const char*)states;
    auto stage = [&](int buf, int t) {
        const char* src = sbase + (size_t)t * 4096;
#pragma unroll
        for (int j = 0; j < 4; ++j)
            gload_lds16(src + srcoff[j], mybuf + buf * 4096 + j * 1024);
    };
    // swizzled LDS read address for element at (row, byte col c)
    auto lds_at = [&](const char* B, int row, int c) -> const void* {
        return (const void*)(B + row * 256 + (c ^ ((row & 7) << 4)));
    };

    stage(0, gw);   // prologue

#pragma unroll
    for (int i = 0; i < TPW; ++i) {
        const int t = gw + i * NWAVES;
        if (i + 1 < TPW) {
            stage((i + 1) & 1, t + NWAVES);          // prefetch next tile
            asm volatile("s_waitcnt vmcnt(4)" ::: "memory");  // cur staged
        } else {
            asm volatile("s_waitcnt vmcnt(0)" ::: "memory");
        }
        __builtin_amdgcn_sched_barrier(0);

        const char* B = mybuf + (i & 1) * 4096;

        // B-operand fragments: S^T[k][n=lo16] = S[lo16][k], contiguous row
        f32x4 a0 = *(const f32x4*)lds_at(B, lo16, g4 * 32);
        f32x4 a1 = *(const f32x4*)lds_at(B, lo16, g4 * 32 + 16);
        f32x4 a2 = *(const f32x4*)lds_at(B, lo16, 128 + g4 * 32);
        f32x4 a3 = *(const f32x4*)lds_at(B, lo16, 128 + g4 * 32 + 16);

        // rv[nb][q] = S[lo16][16nb+4g4+q] -> one b128 per nb (consecutive!)
        f32x4 rv[4];
#pragma unroll
        for (int nb = 0; nb < 4; ++nb)
            rv[nb] = *(const f32x4*)lds_at(B, lo16, nb * 64 + g4 * 16);

        union { bf16x8 v; unsigned u[4]; } af0, af1;
        af0.u[0] = pack2(a0[0], a0[1]);
        af0.u[1] = pack2(a0[2], a0[3]);
        af0.u[2] = pack2(a1[0], a1[1]);
        af0.u[3] = pack2(a1[2], a1[3]);
        af1.u[0] = pack2(a2[0], a2[1]);
        af1.u[1] = pack2(a2[2], a2[3]);
        af1.u[2] = pack2(a3[0], a3[1]);
        af1.u[3] = pack2(a3[2], a3[3]);

        // D = J*S^T + F : row m=16nb+4g4+q (spin), col n=lo16 (batch)
        f32x4 acc[4];
#pragma unroll
        for (int nb = 0; nb < 4; ++nb) acc[nb] = ffrag[nb];
#pragma unroll
        for (int nb = 0; nb < 4; ++nb) {
            acc[nb] = __builtin_amdgcn_mfma_f32_16x16x32_bf16(jf[nb][0], af0.v, acc[nb], 0, 0, 0);
            acc[nb] = __builtin_amdgcn_mfma_f32_16x16x32_bf16(jf[nb][1], af1.v, acc[nb], 0, 0, 0);
        }

        // H[b=lo16] = -sum_m s_b[m] * acc[m][b]; lane-local dot then
        // 2-step reduce across the 4 g4 groups.
        float p = 0.f;
#pragma unroll
        for (int nb = 0; nb < 4; ++nb) {
            p += rv[nb][0] * acc[nb][0];
            p += rv[nb][1] * acc[nb][1];
            p += rv[nb][2] * acc[nb][2];
            p += rv[nb][3] * acc[nb][3];
        }
        p += __shfl_xor(p, 16, 64);
        p += __shfl_xor(p, 32, 64);
        if (g4 == 0)
            out[t * 16 + lo16] = -p;   // lanes 0-15, coalesced 64B
    }
}

extern "C" void kernel_launch(void* const* d_in, const int* in_sizes, int n_in,
                              void* d_out, int out_size, void* d_ws, size_t ws_size,
                              hipStream_t stream) {
    const float* states    = (const float*)d_in[0];
    const float* couplings = (const float*)d_in[1];
    const float* fields    = (const float*)d_in[2];
    float* out = (float*)d_out;
    ham_kernel<<<NBLOCKS, 256, 0, stream>>>(states, couplings, fields, out);
}

// Round 5
// 47.128 us; speedup vs baseline: 1.4155x; 1.0652x over previous
//
#include <hip/hip_runtime.h>

#define NSPIN   64
#define BATCH_N 1000000
#define NTILES  (BATCH_N / 16)    // 62500 16-row tiles
#define NBLOCKS 3125
#define NWAVES  (NBLOCKS * 4)     // 12500 waves
#define TPW     (NTILES / NWAVES) // exactly 5 tiles/wave

typedef __bf16 bf16x8 __attribute__((ext_vector_type(8)));
typedef float  f32x4  __attribute__((ext_vector_type(4)));

// Build symmetric bf16 J (zero diag) from lower-tri coupling vector, once.
__global__ void build_J_kernel(const float* __restrict__ couplings,
                               __bf16* __restrict__ Jg) {
    int idx = blockIdx.x * blockDim.x + threadIdx.x;
    if (idx >= NSPIN * NSPIN) return;
    int r = idx >> 6, c = idx & 63;
    float v = 0.0f;
    if (r > c)      v = couplings[(r * (r - 1)) / 2 + c];
    else if (r < c) v = couplings[(c * (c - 1)) / 2 + r];
    Jg[idx] = (__bf16)v;
}

__device__ __forceinline__ unsigned fbits(float x) {
    union { float f; unsigned u; } cv; cv.f = x; return cv.u;
}
// pack two fp32 into packed bf16x2 (truncation — exact for +/-1.0)
__device__ __forceinline__ unsigned pack2(float lo, float hi) {
    return __builtin_amdgcn_perm(fbits(hi), fbits(lo), 0x07060302u);
}

// async global->LDS, 16B per lane; LDS dest = uniform base + lane*16
__device__ __forceinline__ void gload_lds16(const void* g, void* l) {
    __builtin_amdgcn_global_load_lds(
        (const __attribute__((address_space(1))) unsigned int*)g,
        (__attribute__((address_space(3))) unsigned int*)l, 16, 0, 0);
}

template<bool USE_WS>
__global__ __launch_bounds__(256, 4) void ham_kernel(
    const float* __restrict__ states,
    const float* __restrict__ couplings,
    const float* __restrict__ fields,
    const __bf16* __restrict__ Jg,
    float* __restrict__ out)
{
    // 4 waves x 3 x 4KB wave-private staging buffers (wave w at w*12K).
    // (!USE_WS: first 8KB temporarily holds J during the prologue.)
    __shared__ char smem[48 * 1024];

    const int lane = threadIdx.x & 63;
    const int wid  = threadIdx.x >> 6;
    const int lo16 = lane & 15;   // J row (A) / batch col (D)
    const int g4   = lane >> 4;   // k-group; D rows 4*g4+q
    const int gw   = blockIdx.x * 4 + wid;

    // A fragments (J rows): jf[nb][kb] = J[16nb+lo16][32kb+8g4+e]
    bf16x8 jf[4][2];
    if constexpr (USE_WS) {
#pragma unroll
        for (int nb = 0; nb < 4; ++nb)
#pragma unroll
            for (int kb = 0; kb < 2; ++kb)
                jf[nb][kb] = *(const bf16x8*)(Jg + (nb * 16 + lo16) * NSPIN + kb * 32 + g4 * 8);
    } else {
        __bf16* J = (__bf16*)smem;
        for (int i = threadIdx.x; i < NSPIN * NSPIN; i += 256) {
            int r = i >> 6, c = i & 63;
            float v = 0.0f;
            if (r > c)      v = couplings[(r * (r - 1)) / 2 + c];
            else if (r < c) v = couplings[(c * (c - 1)) / 2 + r];
            J[i] = (__bf16)v;
        }
        __syncthreads();
#pragma unroll
        for (int nb = 0; nb < 4; ++nb)
#pragma unroll
            for (int kb = 0; kb < 2; ++kb)
                jf[nb][kb] = *(const bf16x8*)(J + (nb * 16 + lo16) * NSPIN + kb * 32 + g4 * 8);
        __syncthreads();   // J region becomes wave0's staging buffers
    }

    // acc init = fields along m: ffrag[nb][q] = f[16nb+4g4+q]
    f32x4 ffrag[4];
#pragma unroll
    for (int nb = 0; nb < 4; ++nb)
        ffrag[nb] = *(const f32x4*)(fields + nb * 16 + g4 * 4);

    char* mybuf = smem + wid * (3 * 4096);   // three 4KB buffers, wave-private

    // Per-lane swizzled global source offsets for the 4 staging instrs.
    // LDS[row][chunk] = G[row][chunk ^ (row&7)]  (16B chunks, XOR involution)
    int srcoff[4];
#pragma unroll
    for (int j = 0; j < 4; ++j) {
        int row   = 4 * j + g4;
        int chunk = lo16 ^ (row & 7);
        srcoff[j] = row * 256 + chunk * 16;
    }

    const char* sbase = (const char*)states;
    auto stage = [&](int buf, int t) {
        const char* src = sbase + (size_t)t * 4096;
#pragma unroll
        for (int j = 0; j < 4; ++j)
            gload_lds16(src + srcoff[j], mybuf + buf * 4096 + j * 1024);
    };
    // swizzled LDS read address for element at (row, byte col c)
    auto lds_at = [&](const char* B, int row, int c) -> const void* {
        return (const void*)(B + row * 256 + (c ^ ((row & 7) << 4)));
    };

    // ---- 3-deep pipeline: loads issued 2 compute-phases ahead ----
    stage(0, gw);
    stage(1, gw + NWAVES);

#pragma unroll
    for (int i = 0; i < TPW; ++i) {
        const int t = gw + i * NWAVES;
        if (i + 2 < TPW) {
            stage((i + 2) % 3, t + 2 * NWAVES);
            asm volatile("s_waitcnt vmcnt(8)" ::: "memory");   // tile i staged
        } else if (i + 2 == TPW) {
            asm volatile("s_waitcnt vmcnt(4)" ::: "memory");
        } else {
            asm volatile("s_waitcnt vmcnt(0)" ::: "memory");
        }
        __builtin_amdgcn_sched_barrier(0);

        const char* B = mybuf + (i % 3) * 4096;

        // B-operand fragments: S^T[k][n=lo16] = S[lo16][k], contiguous row
        f32x4 a0 = *(const f32x4*)lds_at(B, lo16, g4 * 32);
        f32x4 a1 = *(const f32x4*)lds_at(B, lo16, g4 * 32 + 16);
        f32x4 a2 = *(const f32x4*)lds_at(B, lo16, 128 + g4 * 32);
        f32x4 a3 = *(const f32x4*)lds_at(B, lo16, 128 + g4 * 32 + 16);

        // rv[nb] = S[lo16][16nb+4g4 .. +3] -> one b128 per nb
        f32x4 rv[4];
#pragma unroll
        for (int nb = 0; nb < 4; ++nb)
            rv[nb] = *(const f32x4*)lds_at(B, lo16, nb * 64 + g4 * 16);

        union { bf16x8 v; unsigned u[4]; } af0, af1;
        af0.u[0] = pack2(a0[0], a0[1]);
        af0.u[1] = pack2(a0[2], a0[3]);
        af0.u[2] = pack2(a1[0], a1[1]);
        af0.u[3] = pack2(a1[2], a1[3]);
        af1.u[0] = pack2(a2[0], a2[1]);
        af1.u[1] = pack2(a2[2], a2[3]);
        af1.u[2] = pack2(a3[0], a3[1]);
        af1.u[3] = pack2(a3[2], a3[3]);

        // D = J*S^T + F : row m=16nb+4g4+q (spin), col n=lo16 (batch)
        f32x4 acc[4];
#pragma unroll
        for (int nb = 0; nb < 4; ++nb) acc[nb] = ffrag[nb];
#pragma unroll
        for (int nb = 0; nb < 4; ++nb) {
            acc[nb] = __builtin_amdgcn_mfma_f32_16x16x32_bf16(jf[nb][0], af0.v, acc[nb], 0, 0, 0);
            acc[nb] = __builtin_amdgcn_mfma_f32_16x16x32_bf16(jf[nb][1], af1.v, acc[nb], 0, 0, 0);
        }

        // H[b=lo16] = -sum_m s_b[m]*acc[m][b]; lane-local dot, 2-step reduce
        float p = 0.f;
#pragma unroll
        for (int nb = 0; nb < 4; ++nb) {
            p += rv[nb][0] * acc[nb][0];
            p += rv[nb][1] * acc[nb][1];
            p += rv[nb][2] * acc[nb][2];
            p += rv[nb][3] * acc[nb][3];
        }
        p += __shfl_xor(p, 16, 64);
        p += __shfl_xor(p, 32, 64);
        if (g4 == 0)
            out[t * 16 + lo16] = -p;   // lanes 0-15, coalesced 64B
    }
}

extern "C" void kernel_launch(void* const* d_in, const int* in_sizes, int n_in,
                              void* d_out, int out_size, void* d_ws, size_t ws_size,
                              hipStream_t stream) {
    const float* states    = (const float*)d_in[0];
    const float* couplings = (const float*)d_in[1];
    const float* fields    = (const float*)d_in[2];
    float* out = (float*)d_out;

    if (ws_size >= NSPIN * NSPIN * sizeof(__bf16)) {
        __bf16* Jg = (__bf16*)d_ws;
        build_J_kernel<<<16, 256, 0, stream>>>(couplings, Jg);
        ham_kernel<true><<<NBLOCKS, 256, 0, stream>>>(states, couplings, fields, Jg, out);
    } else {
        ham_kernel<false><<<NBLOCKS, 256, 0, stream>>>(states, couplings, fields, nullptr, out);
    }
}